// Round 1
// baseline (276.393 us; speedup 1.0000x reference)
//
#include <hip/hip_runtime.h>
#include <hip/hip_bf16.h>

#define NN 100000
#define NE 1600000
#define INF 256
#define OUTF 128
#define NB ((NN + 255) / 256)     // 391
#define NBK ((NN + 127) / 128)    // 782 buckets of 128 nodes
#define CHUNK 8192
#define NBA ((NE + CHUNK - 1) / CHUNK)   // 196
#define NGRP (NN / 32)            // 3125 node-groups (exact: 32*3125=100000)

typedef __attribute__((ext_vector_type(8))) short short8;
typedef __attribute__((ext_vector_type(4))) float f32x4;
typedef __attribute__((ext_vector_type(2))) float f32x2;

static __device__ __forceinline__ short f2bf(float f) {
    __hip_bfloat16 h = __float2bfloat16(f);
    return *reinterpret_cast<short*>(&h);
}

// ---------------------------------------------------------------------------
// Setup: zero deg; block 0: wsv = W@a_src, wdv = W@a_dst;
// blocks 1..8: swizzled bf16 B fragments of W_em.
// Bsw layout: [kt(8)][ct(8)][lane(64)][j(8)]:
//   bf16(Wem[kt*32 + (lane>>4)*8 + j][ct*16 + (lane&15)])
// ---------------------------------------------------------------------------
__global__ void k_setup(const float* __restrict__ W, const float* __restrict__ a,
                        const float* __restrict__ Wem,
                        float* __restrict__ wsv, float* __restrict__ wdv,
                        ushort* __restrict__ Bsw, int* __restrict__ deg) {
    const int b = blockIdx.x, t = threadIdx.x;
    const int i = b * 256 + t;
    if (i < NN) deg[i] = 0;
    if (b == 0) {
        const float* Wr = W + (size_t)t * OUTF;
        float sa = 0.f, sb = 0.f;
        #pragma unroll 8
        for (int k = 0; k < OUTF; ++k) {
            float w = Wr[k];
            sa += w * a[k];
            sb += w * a[OUTF + k];
        }
        wsv[t] = sa;
        wdv[t] = sb;
    } else if (b <= 8) {
        const int kt = b - 1;
        for (int idx = t; idx < 4096; idx += 256) {
            const int ct = idx >> 9;
            const int lane = (idx >> 3) & 63;
            const int j = idx & 7;
            const int k = kt * 32 + (lane >> 4) * 8 + j;
            const int c = ct * 16 + (lane & 15);
            Bsw[((size_t)(kt * 8 + ct) * 64 + lane) * 8 + j] =
                (ushort)f2bf(Wem[(size_t)k * OUTF + c]);
        }
    }
}

// ---------------------------------------------------------------------------
// MFMA matmul: hem(bf16) = x @ W_em; fused f32 s1 = x.ws, s2 = x.wd.
// C/D: col = lane&15, row = (lane>>4)*4 + reg   [m89/m91 verified mapping]
// hem stored SLICED for XCD-L2-resident gathers in k_aggregate:
//   hem[((ct*NN) + row)*16 + c16]  where feature = ct*16 + c16
//   -> slice ct is a contiguous 3.2 MB block (fits one XCD's 4 MiB L2).
// ---------------------------------------------------------------------------
__global__ __launch_bounds__(256) void k_mm(
    const float* __restrict__ x, const ushort* __restrict__ Bsw,
    const float* __restrict__ wsv, const float* __restrict__ wdv,
    float* __restrict__ s1, float* __restrict__ s2, ushort* __restrict__ hem) {
    const int t = threadIdx.x;
    const int w = t >> 6, lane = t & 63;
    const int br = blockIdx.x * 64 + w * 16;
    const int r0 = lane & 15, kq = lane >> 4;
    const int row = br + r0;
    const int rowc = (row < NN) ? row : NN - 1;
    const float* xp = x + (size_t)rowc * INF + kq * 8;
    const short8* bp = reinterpret_cast<const short8*>(Bsw);

    f32x4 acc[8];
    #pragma unroll
    for (int ct = 0; ct < 8; ++ct) acc[ct] = (f32x4){0.f, 0.f, 0.f, 0.f};
    float sa = 0.f, sb = 0.f;

    #pragma unroll
    for (int kt = 0; kt < 8; ++kt) {
        const float4 a0 = *reinterpret_cast<const float4*>(xp + kt * 32);
        const float4 a1 = *reinterpret_cast<const float4*>(xp + kt * 32 + 4);
        const float4 w0 = *reinterpret_cast<const float4*>(wsv + kt * 32 + kq * 8);
        const float4 w1 = *reinterpret_cast<const float4*>(wsv + kt * 32 + kq * 8 + 4);
        const float4 u0 = *reinterpret_cast<const float4*>(wdv + kt * 32 + kq * 8);
        const float4 u1 = *reinterpret_cast<const float4*>(wdv + kt * 32 + kq * 8 + 4);
        sa += a0.x * w0.x + a0.y * w0.y + a0.z * w0.z + a0.w * w0.w
            + a1.x * w1.x + a1.y * w1.y + a1.z * w1.z + a1.w * w1.w;
        sb += a0.x * u0.x + a0.y * u0.y + a0.z * u0.z + a0.w * u0.w
            + a1.x * u1.x + a1.y * u1.y + a1.z * u1.z + a1.w * u1.w;
        short8 af;
        af[0] = f2bf(a0.x); af[1] = f2bf(a0.y); af[2] = f2bf(a0.z); af[3] = f2bf(a0.w);
        af[4] = f2bf(a1.x); af[5] = f2bf(a1.y); af[6] = f2bf(a1.z); af[7] = f2bf(a1.w);
        #pragma unroll
        for (int ct = 0; ct < 8; ++ct) {
            const short8 bf = bp[(size_t)(kt * 8 + ct) * 64 + lane];
            acc[ct] = __builtin_amdgcn_mfma_f32_16x16x32_bf16(af, bf, acc[ct], 0, 0, 0);
        }
    }

    sa += __shfl_xor(sa, 16); sa += __shfl_xor(sa, 32);
    sb += __shfl_xor(sb, 16); sb += __shfl_xor(sb, 32);
    if (kq == 0 && row < NN) { s1[row] = sa; s2[row] = sb; }

    #pragma unroll
    for (int ct = 0; ct < 8; ++ct) {
        #pragma unroll
        for (int i = 0; i < 4; ++i) {
            const int rr = br + kq * 4 + i;
            if (rr < NN)
                hem[((size_t)ct * NN + rr) * 16 + r0] = (ushort)f2bf(acc[ct][i]);
        }
    }
}

// ---------------------------------------------------------------------------
// Degree histogram only (ee compute moved into k_binA).
// ---------------------------------------------------------------------------
__global__ void k_deg(const int* __restrict__ src, int* __restrict__ deg) {
    const int e = blockIdx.x * 256 + threadIdx.x;
    if (e < NE) atomicAdd(&deg[src[e]], 1);
}

// ---------------------------------------------------------------------------
// 3-level scan
// ---------------------------------------------------------------------------
__global__ void k_bsum(const int* __restrict__ deg, int* __restrict__ bsum) {
    __shared__ int sm[256];
    const int t = threadIdx.x;
    const int i = blockIdx.x * 256 + t;
    sm[t] = (i < NN) ? deg[i] : 0;
    __syncthreads();
    for (int off = 128; off > 0; off >>= 1) {
        if (t < off) sm[t] += sm[t + off];
        __syncthreads();
    }
    if (t == 0) bsum[blockIdx.x] = sm[0];
}

__global__ void k_bscan(const int* __restrict__ bsum, int* __restrict__ bpre) {
    __shared__ int sm[512];
    const int t = threadIdx.x;
    const int v = (t < NB) ? bsum[t] : 0;
    sm[t] = v;
    __syncthreads();
    for (int off = 1; off < 512; off <<= 1) {
        const int add = (t >= off) ? sm[t - off] : 0;
        __syncthreads();
        sm[t] += add;
        __syncthreads();
    }
    if (t < NB) bpre[t] = sm[t] - v;   // exclusive
}

// per-node exclusive offsets + sentinel offs[NN]=NE + bucket cursor init
__global__ void k_offs(const int* __restrict__ deg, const int* __restrict__ bpre,
                       int* __restrict__ offs, int* __restrict__ bcur) {
    __shared__ int sm[256];
    const int t = threadIdx.x;
    const int i = blockIdx.x * 256 + t;
    const int v = (i < NN) ? deg[i] : 0;
    sm[t] = v;
    __syncthreads();
    for (int off = 1; off < 256; off <<= 1) {
        const int add = (t >= off) ? sm[t - off] : 0;
        __syncthreads();
        sm[t] += add;
        __syncthreads();
    }
    const int excl = sm[t] - v + bpre[blockIdx.x];
    if (i < NN) {
        offs[i] = excl;
        if ((i & 127) == 0) bcur[i >> 7] = excl;
        if (i == NN - 1) offs[NN] = excl + v;
    }
}

// ---------------------------------------------------------------------------
// Pass A (fused with edge_e): compute ee = s1[s]+s2[d], write edge_e output,
// quantize v = exp(sigmoid(ee)) in (1,e) to 15-bit fixed point
// (vq = round((v-1)*16384), abs err <= 3e-5), then bucket edges (bucket =
// src>>7) into contiguous per-bucket runs.
// ebA record: { (dst<<7) | (src&127), vq }
// ---------------------------------------------------------------------------
__global__ __launch_bounds__(256) void k_binA(
    const int* __restrict__ src, const int* __restrict__ dst,
    const float* __restrict__ s1, const float* __restrict__ s2,
    float* __restrict__ ee_out, int* __restrict__ bcur,
    int2* __restrict__ ebA) {
    __shared__ int cnt[NBK];
    __shared__ int base[NBK];
    const int t = threadIdx.x;
    const int e0 = blockIdx.x * CHUNK;

    for (int i = t; i < NBK; i += 256) cnt[i] = 0;
    __syncthreads();
    for (int i = t; i < CHUNK; i += 256) {
        const int e = e0 + i;
        if (e < NE) atomicAdd(&cnt[src[e] >> 7], 1);
    }
    __syncthreads();
    for (int i = t; i < NBK; i += 256) {
        const int c = cnt[i];
        base[i] = (c > 0) ? atomicAdd(&bcur[i], c) : 0;
    }
    __syncthreads();
    for (int i = t; i < NBK; i += 256) cnt[i] = 0;
    __syncthreads();
    for (int i = t; i < CHUNK; i += 256) {
        const int e = e0 + i;
        if (e < NE) {
            const int s = src[e], d = dst[e];
            const float ee = s1[s] + s2[d];
            ee_out[e] = ee;
            const float ob = 1.f / (1.f + __expf(-ee));
            const float v = __expf(ob);                   // in (1, e)
            int vq = (int)((v - 1.f) * 16384.f + 0.5f);   // <= 28147
            vq = (vq > 32767) ? 32767 : vq;
            const int bk = s >> 7;
            const int r = atomicAdd(&cnt[bk], 1);
            ebA[base[bk] + r] = make_int2((d << 7) | (s & 127), vq);
        }
    }
}

// ---------------------------------------------------------------------------
// Pass B: one block per bucket; LDS per-node cursors; scatter within the
// block-local CSR region. Emits 4-byte records: (dst<<15) | vq.
// (dst < 2^17, vq < 2^15 -> exactly 32 bits)
// ---------------------------------------------------------------------------
__global__ __launch_bounds__(256) void k_sortB(
    const int* __restrict__ offs, const int2* __restrict__ ebA,
    uint* __restrict__ ebB) {
    __shared__ int cur[128];
    const int b = blockIdx.x, t = threadIdx.x;
    const int n0 = b << 7;
    const int lo = offs[n0];
    const int nhi = (n0 + 128 < NN) ? n0 + 128 : NN;
    const int hi = offs[nhi];
    if (t < 128) {
        const int node = n0 + t;
        cur[t] = (node < NN) ? (offs[node] - lo) : 0;
    }
    __syncthreads();
    for (int i = lo + t; i < hi; i += 256) {
        const int2 r = ebA[i];
        const int sidx = r.x & 127;
        const uint d = ((unsigned)r.x) >> 7;
        const int p = atomicAdd(&cur[sidx], 1);
        ebB[lo + p] = (d << 15) | (uint)r.y;
    }
}

// ---------------------------------------------------------------------------
// Aggregation, XCD-pinned feature-sliced:
//   slice = blockIdx & 7  -> fixed XCD (round-robin dispatch heuristic),
//   so each XCD only gathers its own contiguous 3.2 MB hem slice -> L2-resident.
// Wave = 8 nodes x 8 feature-lanes; lane owns (node, feat-pair) privately:
// no cross-lane reductions (dsum replicates across a node's 8 lanes for free).
// ---------------------------------------------------------------------------
__global__ __launch_bounds__(256) void k_aggregate(
    const uint* __restrict__ eb, const int* __restrict__ offs,
    const int* __restrict__ deg, const ushort* __restrict__ hem,
    float* __restrict__ out0) {
    const int slice = blockIdx.x & 7;
    const int grp = blockIdx.x >> 3;
    const int t = threadIdx.x;
    const int node = grp * 32 + (t >> 3);   // NN = 32*NGRP exactly, no tail
    const int f = t & 7;                     // feature-pair within slice
    const uint* hemS = reinterpret_cast<const uint*>(hem)
                     + (size_t)slice * NN * 8 + f;
    const int beg = offs[node];
    const int cnt = deg[node];

    float a0 = 0.f, a1 = 0.f, dsum = 0.f;
    int j = 0;
    for (; j + 2 <= cnt; j += 2) {
        const uint r0 = eb[beg + j];
        const uint r1 = eb[beg + j + 1];
        const float v0 = 1.f + (float)(r0 & 0x7fffu) * (1.f / 16384.f);
        const float v1 = 1.f + (float)(r1 & 0x7fffu) * (1.f / 16384.f);
        const uint u0 = hemS[(size_t)(r0 >> 15) * 8];
        const uint u1 = hemS[(size_t)(r1 >> 15) * 8];
        a0 += v0 * __uint_as_float(u0 << 16) + v1 * __uint_as_float(u1 << 16);
        a1 += v0 * __uint_as_float(u0 & 0xffff0000u)
            + v1 * __uint_as_float(u1 & 0xffff0000u);
        dsum += v0 + v1;
    }
    if (j < cnt) {
        const uint r0 = eb[beg + j];
        const float v0 = 1.f + (float)(r0 & 0x7fffu) * (1.f / 16384.f);
        const uint u0 = hemS[(size_t)(r0 >> 15) * 8];
        a0 += v0 * __uint_as_float(u0 << 16);
        a1 += v0 * __uint_as_float(u0 & 0xffff0000u);
        dsum += v0;
    }
    const float inv = (cnt > 0) ? 1.f / dsum : 0.f;
    f32x2 o;
    o.x = a0 * inv;
    o.y = a1 * inv;
    __builtin_nontemporal_store(o, reinterpret_cast<f32x2*>(
        out0 + (size_t)node * OUTF + slice * 16 + f * 2));
}

// ---------------------------------------------------------------------------
extern "C" void kernel_launch(void* const* d_in, const int* in_sizes, int n_in,
                              void* d_out, int out_size, void* d_ws, size_t ws_size,
                              hipStream_t stream) {
    const float* x   = (const float*)d_in[0];
    const int* eidx  = (const int*)d_in[1];
    const float* W   = (const float*)d_in[2];
    const float* a   = (const float*)d_in[3];
    const float* Wem = (const float*)d_in[4];

    const int* src = eidx;
    const int* dst = eidx + NE;

    float* out0 = (float*)d_out;            // h_prime: NN*128
    float* out1 = out0 + (size_t)NN * OUTF; // edge_e: NE

    // workspace layout (~46.5 MB), 16B-aligned chunks
    float* wsv   = (float*)d_ws;                     // 256
    float* wdv   = wsv + 256;                        // 256
    float* s1    = wdv + 256;                        // NN
    float* s2    = s1 + NN;                          // NN
    ushort* hem  = (ushort*)(s2 + NN);               // NN*128 bf16 (sliced layout)
    ushort* Bsw  = hem + (size_t)NN * OUTF;          // 32768
    int* deg     = (int*)(Bsw + 32768);              // NN
    int* offs    = deg + NN;                         // NN+4 (sentinel + pad)
    int* bsum    = offs + NN + 4;                    // 512
    int* bpre    = bsum + 512;                       // 512
    int* bcur    = bpre + 512;                       // 784 (NBK padded)
    int2* ebA    = (int2*)(bcur + 784);              // NE * 8B
    uint* ebB    = (uint*)(ebA + NE);                // NE * 4B

    hipLaunchKernelGGL(k_setup, dim3(NB), dim3(256), 0, stream,
                       W, a, Wem, wsv, wdv, Bsw, deg);
    hipLaunchKernelGGL(k_mm, dim3((NN + 63) / 64), dim3(256), 0, stream,
                       x, Bsw, wsv, wdv, s1, s2, hem);
    hipLaunchKernelGGL(k_deg, dim3((NE + 255) / 256), dim3(256), 0, stream,
                       src, deg);
    hipLaunchKernelGGL(k_bsum, dim3(NB), dim3(256), 0, stream, deg, bsum);
    hipLaunchKernelGGL(k_bscan, dim3(1), dim3(512), 0, stream, bsum, bpre);
    hipLaunchKernelGGL(k_offs, dim3(NB), dim3(256), 0, stream, deg, bpre, offs, bcur);
    hipLaunchKernelGGL(k_binA, dim3(NBA), dim3(256), 0, stream,
                       src, dst, s1, s2, out1, bcur, ebA);
    hipLaunchKernelGGL(k_sortB, dim3(NBK), dim3(256), 0, stream, offs, ebA, ebB);
    hipLaunchKernelGGL(k_aggregate, dim3(8 * NGRP), dim3(256), 0, stream,
                       ebB, offs, deg, hem, out0);
}